// Round 9
// baseline (93.679 us; speedup 1.0000x reference)
//
#include <hip/hip_runtime.h>
#include <hip/hip_bf16.h>
#include <cstdint>

#define BATCH 8192
#define DIM   128
#define MARGIN 1.0f

typedef __attribute__((ext_vector_type(8))) short short8;
typedef __attribute__((ext_vector_type(4))) float f32x4;
typedef __attribute__((ext_vector_type(4))) int   i32x4;

// async 16B global -> LDS; LDS dst = wave-uniform base, HW adds lane*16
__device__ __forceinline__ void async_copy16(const void* g, void* lds) {
    __builtin_amdgcn_global_load_lds(
        (const __attribute__((address_space(1))) unsigned int*)g,
        (__attribute__((address_space(3))) unsigned int*)lds, 16, 0, 0);
}

// ---------------------------------------------------------------------------
// Kernel 1: fp32 -> bf16 convert, per-row squared norms (fp32-exact),
// init hp2 (max-accum, 0) / hn2 (min-accum, +inf).
// ---------------------------------------------------------------------------
__global__ __launch_bounds__(256) void bhtl_prep(
    const float* __restrict__ emb,
    __hip_bfloat16* __restrict__ Ebf,
    float* __restrict__ sq,
    unsigned* __restrict__ hp2,
    unsigned* __restrict__ hn2)
{
    const int w   = threadIdx.x >> 6;
    const int l   = threadIdx.x & 63;
    const int row = blockIdx.x * 4 + w;
    const float2 e = ((const float2*)(emb + row * DIM))[l];
    __hip_bfloat162 h2;
    h2.x = __float2bfloat16(e.x);
    h2.y = __float2bfloat16(e.y);
    ((__hip_bfloat162*)(Ebf + row * DIM))[l] = h2;
    float s = e.x * e.x + e.y * e.y;
    #pragma unroll
    for (int d = 1; d < 64; d <<= 1) s += __shfl_xor(s, d, 64);
    if (l == 0) {
        sq[row]  = s;
        hp2[row] = 0u;           // max accumulator (non-negative domain)
        hn2[row] = 0x7F800000u;  // +inf (min accumulator)
    }
}

// ---------------------------------------------------------------------------
// Kernel 2: fused E @ E^T + hardest-pos/neg selection.
// ZERO-BARRIER wave-self-pipelined + EXPLICIT vmcnt wait (R8 fix):
//   global_load_lds has NO register dependency -> the compiler never waits
//   on it except at __syncthreads (m97 asm). With no barrier we must place
//   the wait by hand: one `s_waitcnt vmcnt(0)` (memory-clobber asm) at the
//   top of each chunk iteration. It drains only the 8 glds issued for this
//   chunk ONE ITERATION EARLIER (~650 cyc of MFMA+epilogue in flight) —
//   the AITER fine-grained-vmcnt pipeline, expressed in HIP.
//   1024 blocks = 64 row-tiles x 16 col-splits, 128 threads (2 waves).
//   Wave: 64 rows (af[4][4] = 64 VGPRs) x 512 cols in 16 chunks of 32 cols.
//   Each wave owns a PRIVATE 2x8KB LDS slice (no cross-wave hazards).
//   Prefetch targets buf^1 whose prior reads were consumed (lgkmcnt) in the
//   previous iteration -> no WAR hazard.
// XOR swizzle on the GLOBAL side (validated R6/R7, absmax 0): stored unit
//   (col,u) holds global 16B-chunk u^(col&7); fragment read at unit
//   (kc*4+q)^(ln&7) retrieves chunk kc*4+q since col&7 == ln&7.
// Transposed MFMA (validated R4-R7): acc = mfma(B, A); lane (q,ln) elem r ->
//   row = rowbase+m*16+ln, col = jb+n*16+q*4+r.
// LDS 40 KB/block -> 4 blocks/CU; ~190 VGPR -> 2 waves/SIMD (8 waves/CU).
// Atomics fire-and-forget, NO fence (R5 lesson).
// ---------------------------------------------------------------------------
__global__ __launch_bounds__(128) void bhtl_main(
    const __hip_bfloat16* __restrict__ Ebf,
    const float* __restrict__ sq,
    const int* __restrict__ labels,
    unsigned* __restrict__ hp2,
    unsigned* __restrict__ hn2)
{
    __shared__ __align__(16) unsigned short B_s[2][2][4096];  // [wave][buf] 8 KB
    __shared__ __align__(16) float sqm[2][512];               // per-wave meta
    __shared__ __align__(16) int   labm[2][512];

    const int tid  = threadIdx.x;
    const int w    = tid >> 6;
    const int lane = tid & 63;
    const int q    = lane >> 4;
    const int ln   = lane & 15;
    const int rt   = blockIdx.x >> 4;          // 0..63 row tile
    const int js   = blockIdx.x & 15;          // 0..15 col split
    const int rowbase = rt * 128 + w * 64;
    const int jbase   = js * 512;

    // ---- stage per-wave column meta (512 cols, wave-private) ----
    #pragma unroll
    for (int c = 0; c < 2; ++c) {
        int U = c * 64 + lane;                 // 16B unit = 4 f32
        async_copy16(sq     + jbase + U * 4, &sqm [w][c * 256]);
        async_copy16(labels + jbase + U * 4, &labm[w][c * 256]);
    }

    // ---- B chunk stager: 32 cols x 256 B = 512 units = 8 glds ----
    auto stageB = [&](int buf, int ch) {
        const int jb = jbase + ch * 32;
        #pragma unroll
        for (int c = 0; c < 8; ++c) {
            int U   = c * 64 + lane;
            int col = U >> 4;                  // 0..31
            int u   = U & 15;
            int j   = u ^ (col & 7);           // global-side swizzle
            async_copy16(Ebf + (size_t)(jb + col) * DIM + j * 8,
                         &B_s[w][buf][c * 64 * 8]);
        }
    };

    // ---- A fragments (64 rows, K=128) + row metadata ----
    short8 af[4][4];
    float  sqi[4];
    int    labi[4];
    #pragma unroll
    for (int m = 0; m < 4; ++m) {
        const int row = rowbase + m * 16 + ln;
        #pragma unroll
        for (int kc = 0; kc < 4; ++kc)
            af[m][kc] = *(const short8*)(Ebf + (size_t)row * DIM + kc * 32 + q * 8);
        sqi[m]  = sq[row];
        labi[m] = labels[row];
    }

    float mp[4] = {-INFINITY, -INFINITY, -INFINITY, -INFINITY};
    float mn[4] = { INFINITY,  INFINITY,  INFINITY,  INFINITY};

    stageB(0, 0);

    #pragma unroll 2
    for (int ch = 0; ch < 16; ++ch) {
        const int buf = ch & 1;

        // 0) THE WAIT: drain this chunk's glds (issued one iteration ago).
        //    Memory clobber pins the ds_reads below it.
        asm volatile("s_waitcnt vmcnt(0)" ::: "memory");

        // 1) all LDS reads for chunk ch (fragments + meta)
        short8 bfr[2][4];
        #pragma unroll
        for (int n = 0; n < 2; ++n)
            #pragma unroll
            for (int kc = 0; kc < 4; ++kc)
                bfr[n][kc] = *(const short8*)(
                    &B_s[w][buf][((n * 16 + ln) * 16 + (((kc * 4 + q) ^ (ln & 7)))) * 8]);
        f32x4 sqj[2];
        i32x4 labj[2];
        #pragma unroll
        for (int n = 0; n < 2; ++n) {
            sqj[n]  = *(const f32x4*)(&sqm [w][ch * 32 + n * 16 + q * 4]);
            labj[n] = *(const i32x4*)(&labm[w][ch * 32 + n * 16 + q * 4]);
        }

        // 2) prefetch next chunk into the other half of the private slice
        if (ch < 15) stageB(buf ^ 1, ch + 1);

        // 3) compute on chunk ch
        f32x4 acc[4][2];
        const f32x4 zero = {0.f, 0.f, 0.f, 0.f};
        #pragma unroll
        for (int m = 0; m < 4; ++m)
            #pragma unroll
            for (int n = 0; n < 2; ++n) acc[m][n] = zero;
        #pragma unroll
        for (int kc = 0; kc < 4; ++kc)
            #pragma unroll
            for (int m = 0; m < 4; ++m)
                #pragma unroll
                for (int n = 0; n < 2; ++n)
                    acc[m][n] = __builtin_amdgcn_mfma_f32_16x16x32_bf16(
                        bfr[n][kc], af[m][kc], acc[m][n], 0, 0, 0);   // transposed

        #pragma unroll
        for (int m = 0; m < 4; ++m)
            #pragma unroll
            for (int n = 0; n < 2; ++n)
                #pragma unroll
                for (int r = 0; r < 4; ++r) {
                    float val = fmaf(-2.0f, acc[m][n][r], sqj[n][r]);
                    bool same = (labi[m] == labj[n][r]);
                    mp[m] = fmaxf(mp[m], same ? val : -INFINITY);
                    mn[m] = fminf(mn[m], same ? INFINITY : val);
                }
    }

    // ---- reduce over the 4 q-lanes sharing each row, then atomics ----
    #pragma unroll
    for (int m = 0; m < 4; ++m) {
        float a = mp[m], b = mn[m];
        a = fmaxf(a, __shfl_xor(a, 16, 64));
        a = fmaxf(a, __shfl_xor(a, 32, 64));
        b = fminf(b, __shfl_xor(b, 16, 64));
        b = fminf(b, __shfl_xor(b, 32, 64));
        if (q == 0) {
            const int row = rowbase + m * 16 + ln;
            atomicMax(&hp2[row], __float_as_uint(fmaxf(sqi[m] + a, 0.0f)));
            atomicMin(&hn2[row], __float_as_uint(fmaxf(sqi[m] + b, 0.0f)));
        }
    }
}

// ---------------------------------------------------------------------------
// Kernel 3: per-anchor loss + mean. Single block, deterministic output.
// ---------------------------------------------------------------------------
__global__ __launch_bounds__(1024) void bhtl_final(
    const unsigned* __restrict__ hp2,
    const unsigned* __restrict__ hn2,
    float* __restrict__ out)
{
    __shared__ float red[16];
    float sum = 0.f;
    for (int i = threadIdx.x; i < BATCH; i += 1024) {
        float hp = sqrtf(__uint_as_float(hp2[i]));
        float hn = sqrtf(__uint_as_float(hn2[i]));
        sum += fmaxf(hp - hn + MARGIN, 0.f);
    }
    #pragma unroll
    for (int d = 1; d < 64; d <<= 1) sum += __shfl_xor(sum, d, 64);
    int wv = threadIdx.x >> 6;
    if ((threadIdx.x & 63) == 0) red[wv] = sum;
    __syncthreads();
    if (threadIdx.x < 64) {
        float v = (threadIdx.x < 16) ? red[threadIdx.x] : 0.f;
        #pragma unroll
        for (int d = 1; d < 16; d <<= 1) v += __shfl_xor(v, d, 64);
        if (threadIdx.x == 0) out[0] = v / (float)BATCH;
    }
}

// ---------------------------------------------------------------------------
extern "C" void kernel_launch(void* const* d_in, const int* in_sizes, int n_in,
                              void* d_out, int out_size, void* d_ws, size_t ws_size,
                              hipStream_t stream)
{
    const float* emb    = (const float*)d_in[0];
    const int*   labels = (const int*)d_in[1];
    float*       out    = (float*)d_out;

    char* ws = (char*)d_ws;
    __hip_bfloat16* Ebf = (__hip_bfloat16*)ws;                        // 2 MiB
    float*    sq   = (float*)   (ws + 2 * 1024 * 1024);               // 32 KiB
    unsigned* hp2  = (unsigned*)(ws + 2 * 1024 * 1024 + 32 * 1024);   // 32 KiB
    unsigned* hn2  = (unsigned*)(ws + 2 * 1024 * 1024 + 64 * 1024);   // 32 KiB

    bhtl_prep<<<BATCH / 4, 256, 0, stream>>>(emb, Ebf, sq, hp2, hn2);
    bhtl_main<<<1024, 128, 0, stream>>>(Ebf, sq, labels, hp2, hn2);
    bhtl_final<<<1, 1024, 0, stream>>>(hp2, hn2, out);
}

// Round 10
// 87.640 us; speedup vs baseline: 1.0689x; 1.0689x over previous
//
#include <hip/hip_runtime.h>
#include <hip/hip_bf16.h>
#include <cstdint>

#define BATCH 8192
#define DIM   128
#define KAUG  160          // 128 data + 10 label dims + 22 zero pad
#define MARGIN 1.0f
#define SEP    8192.0f     // 2 * 64^2 label separator (exact in fp32/bf16)

typedef __attribute__((ext_vector_type(8))) short short8;
typedef __attribute__((ext_vector_type(4))) float f32x4;

// async 16B global -> LDS; LDS dst = wave-uniform base, HW adds lane*16
__device__ __forceinline__ void async_copy16(const void* g, void* lds) {
    __builtin_amdgcn_global_load_lds(
        (const __attribute__((address_space(1))) unsigned int*)g,
        (__attribute__((address_space(3))) unsigned int*)lds, 16, 0, 0);
}

// ---------------------------------------------------------------------------
// Kernel 1: build label-AUGMENTED bf16 matrices.
//   EbfA row i: [bf16(e_i), +64*onehot(lab_i), 0...]   (160 dims)
//   EbfB row j: [bf16(e_j), -64*onehot(lab_j), 0...]
//   dot_aug = <A_i, B_j> = dot - 4096*[same]  ->  val = sqj - 2*dot_aug
//           = (sqj - 2*dot) + 8192*[same]: label selection becomes pure
//   max/min in the epilogue (3 VALU/pair instead of 6, no label loads).
// Also: per-row squared norms over the 128 REAL dims; init hp2/hn2.
// ---------------------------------------------------------------------------
__global__ __launch_bounds__(256) void bhtl_prep(
    const float* __restrict__ emb,
    const int* __restrict__ labels,
    __hip_bfloat16* __restrict__ EbfA,
    __hip_bfloat16* __restrict__ EbfB,
    float* __restrict__ sq,
    unsigned* __restrict__ hp2,
    unsigned* __restrict__ hn2)
{
    const int w   = threadIdx.x >> 6;
    const int l   = threadIdx.x & 63;
    const int row = blockIdx.x * 4 + w;
    const float2 e = ((const float2*)(emb + row * DIM))[l];
    __hip_bfloat162 h2;
    h2.x = __float2bfloat16(e.x);
    h2.y = __float2bfloat16(e.y);
    ((__hip_bfloat162*)(EbfA + (size_t)row * KAUG))[l] = h2;
    ((__hip_bfloat162*)(EbfB + (size_t)row * KAUG))[l] = h2;
    if (l < 16) {   // augmented dims 128 + 2l, 129 + 2l
        const int lab = labels[row];
        const float a0 = (2 * l     == lab) ? 64.f : 0.f;
        const float a1 = (2 * l + 1 == lab) ? 64.f : 0.f;
        __hip_bfloat162 hA, hB;
        hA.x = __float2bfloat16(a0);  hA.y = __float2bfloat16(a1);
        hB.x = __float2bfloat16(-a0); hB.y = __float2bfloat16(-a1);
        ((__hip_bfloat162*)(EbfA + (size_t)row * KAUG + DIM))[l] = hA;
        ((__hip_bfloat162*)(EbfB + (size_t)row * KAUG + DIM))[l] = hB;
    }
    float s = e.x * e.x + e.y * e.y;
    #pragma unroll
    for (int d = 1; d < 64; d <<= 1) s += __shfl_xor(s, d, 64);
    if (l == 0) {
        sq[row]  = s;
        hp2[row] = 0u;           // max accumulator (clamped non-negative)
        hn2[row] = 0x7F800000u;  // +inf (min accumulator)
    }
}

// ---------------------------------------------------------------------------
// Kernel 2: fused augmented E_A @ E_B^T + max/min epilogue.
// Zero-barrier, wave-self-pipelined, DEPTH-2 prefetch:
//   1024 blocks = 64 row-tiles x 16 col-splits, 128 threads (2 waves).
//   Wave: 64 rows x 512 cols in 32 chunks of 16 cols (K=160).
//   3 wave-private LDS buffers (5 KB each); chunk ch+2 staged during iter ch;
//   `s_waitcnt vmcnt(5)` at iter top waits for the OLDEST 5 glds (chunk ch)
//   while chunk ch+1's 5 stay in flight -> ~2 iterations (~700 cyc) latency
//   cover (R9's depth-1 vmcnt(0) covered only ~1 iter and didn't help).
// Loop unrolled in groups of 3 so buffer indices are compile-time.
// XOR swizzle on the GLOBAL side for units 0..15 of each col's 20 16B-units
//   (units 16..19 unswizzled: 2-group aliasing, minor).
// Transposed MFMA (validated R4-R9): acc = mfma(B, A); lane (q,ln) elem r ->
//   row = rowbase + m*16 + ln, col = jb + q*4 + r.
// Epilogue: val = fmaf(-2, acc, sqj); mp = max; mn = min. 3 VALU/pair.
// LDS 34 KB -> 4 blocks/CU. Atomics fire-and-forget, NO fence (R5).
// ---------------------------------------------------------------------------
__global__ __launch_bounds__(128) void bhtl_main(
    const __hip_bfloat16* __restrict__ EbfA,
    const __hip_bfloat16* __restrict__ EbfB,
    const float* __restrict__ sq,
    unsigned* __restrict__ hp2,
    unsigned* __restrict__ hn2)
{
    __shared__ __align__(16) unsigned short B_s[2][3][2560];  // [wave][buf] 5 KB
    __shared__ __align__(16) float sqm[2][512];               // per-wave col sq

    const int tid  = threadIdx.x;
    const int w    = tid >> 6;
    const int lane = tid & 63;
    const int q    = lane >> 4;
    const int ln   = lane & 15;
    const int rt   = blockIdx.x >> 4;          // 0..63 row tile
    const int js   = blockIdx.x & 15;          // 0..15 col split
    const int rowbase = rt * 128 + w * 64;
    const int jbase   = js * 512;

    // ---- A fragments (64 rows, K=160), pinned in 80 VGPRs ----
    short8 af[4][5];
    #pragma unroll
    for (int m = 0; m < 4; ++m)
        #pragma unroll
        for (int kc = 0; kc < 5; ++kc) {
            af[m][kc] = *(const short8*)(
                EbfA + (size_t)(rowbase + m * 16 + ln) * KAUG + kc * 32 + q * 8);
            asm("" : "+v"(af[m][kc]));
        }

    // ---- stage per-wave col sq (512 floats = 2 KB = 2 glds) ----
    #pragma unroll
    for (int c = 0; c < 2; ++c)
        async_copy16(sq + jbase + (c * 64 + lane) * 4, &sqm[w][c * 256]);

    // ensure all prologue vmem (af loads + meta glds) drained before the
    // counted pipeline starts; memory clobber pins ordering
    asm volatile("s_waitcnt vmcnt(0)" ::: "memory");

    // ---- B chunk stager: 16 cols x 320 B = 320 units = 5 glds ----
    auto stageB = [&](int buf, int ch) {
        const int jb = jbase + ch * 16;
        #pragma unroll
        for (int c = 0; c < 5; ++c) {
            int U   = c * 64 + lane;           // 0..319
            int col = U / 20;                  // 0..15 (const-div -> mulhi)
            int u   = U - col * 20;            // 0..19
            int g   = (u < 16) ? (u ^ (col & 7)) : u;   // global-side swizzle
            async_copy16(EbfB + (size_t)(jb + col) * KAUG + g * 8,
                         &B_s[w][buf][c * 512]);
        }
    };

    float mp[4] = {-INFINITY, -INFINITY, -INFINITY, -INFINITY};
    float mn[4] = { INFINITY,  INFINITY,  INFINITY,  INFINITY};

    auto doIter = [&](int ch, int buf, bool doStage, bool last) {
        if (last) asm volatile("s_waitcnt vmcnt(0)" ::: "memory");
        else      asm volatile("s_waitcnt vmcnt(5)" ::: "memory");

        // LDS reads for chunk ch
        short8 bfr[5];
        #pragma unroll
        for (int kc = 0; kc < 5; ++kc) {
            const int t    = kc * 4 + q;                       // global unit
            const int unit = (kc < 4) ? (t ^ (ln & 7)) : t;    // stored unit
            bfr[kc] = *(const short8*)(&B_s[w][buf][(ln * 20 + unit) * 8]);
        }
        f32x4 sqj = *(const f32x4*)(&sqm[w][ch * 16 + q * 4]);

        // prefetch chunk ch+2 (depth-2)
        if (doStage) stageB(buf == 0 ? 2 : buf - 1, ch + 2);   // (buf+2)%3

        // MFMA: 4 row-blocks x 1 col-block x K=160
        f32x4 acc[4];
        const f32x4 zero = {0.f, 0.f, 0.f, 0.f};
        #pragma unroll
        for (int m = 0; m < 4; ++m) acc[m] = zero;
        #pragma unroll
        for (int kc = 0; kc < 5; ++kc)
            #pragma unroll
            for (int m = 0; m < 4; ++m)
                acc[m] = __builtin_amdgcn_mfma_f32_16x16x32_bf16(
                    bfr[kc], af[m][kc], acc[m], 0, 0, 0);      // transposed

        // epilogue: 3 VALU per pair, label logic already inside the dot
        #pragma unroll
        for (int m = 0; m < 4; ++m)
            #pragma unroll
            for (int r = 0; r < 4; ++r) {
                float val = fmaf(-2.0f, acc[m][r], sqj[r]);
                mp[m] = fmaxf(mp[m], val);
                mn[m] = fminf(mn[m], val);
            }
    };

    stageB(0, 0);
    stageB(1, 1);

    #pragma unroll 1
    for (int base = 0; base < 30; base += 3) {
        doIter(base,     0, true, false);
        doIter(base + 1, 1, true, false);
        doIter(base + 2, 2, base + 2 < 30, false);   // ch=29 stages 31; no stage past 31
    }
    doIter(30, 0, false, false);
    doIter(31, 1, false, true);

    // ---- reduce over the 4 q-lanes sharing each row, then atomics ----
    #pragma unroll
    for (int m = 0; m < 4; ++m) {
        float a = mp[m], b = mn[m];
        a = fmaxf(a, __shfl_xor(a, 16, 64));
        a = fmaxf(a, __shfl_xor(a, 32, 64));
        b = fminf(b, __shfl_xor(b, 16, 64));
        b = fminf(b, __shfl_xor(b, 32, 64));
        if (q == 0) {
            const int row = rowbase + m * 16 + ln;
            const float sqi = sq[row];
            // hardest-pos^2 = sqi + (max val) - SEP; hardest-neg^2 = sqi + min val
            // clamp >=0: uint order == float order; splits with no same-class
            // col give negative -> clamp 0 -> atomicMax no-op (self-correct)
            atomicMax(&hp2[row], __float_as_uint(fmaxf(sqi + a - SEP, 0.0f)));
            atomicMin(&hn2[row], __float_as_uint(fmaxf(sqi + b, 0.0f)));
        }
    }
}

// ---------------------------------------------------------------------------
// Kernel 3: per-anchor loss + mean. Single block, deterministic output.
// ---------------------------------------------------------------------------
__global__ __launch_bounds__(1024) void bhtl_final(
    const unsigned* __restrict__ hp2,
    const unsigned* __restrict__ hn2,
    float* __restrict__ out)
{
    __shared__ float red[16];
    float sum = 0.f;
    for (int i = threadIdx.x; i < BATCH; i += 1024) {
        float hp = sqrtf(__uint_as_float(hp2[i]));
        float hn = sqrtf(__uint_as_float(hn2[i]));
        sum += fmaxf(hp - hn + MARGIN, 0.f);
    }
    #pragma unroll
    for (int d = 1; d < 64; d <<= 1) sum += __shfl_xor(sum, d, 64);
    int wv = threadIdx.x >> 6;
    if ((threadIdx.x & 63) == 0) red[wv] = sum;
    __syncthreads();
    if (threadIdx.x < 64) {
        float v = (threadIdx.x < 16) ? red[threadIdx.x] : 0.f;
        #pragma unroll
        for (int d = 1; d < 16; d <<= 1) v += __shfl_xor(v, d, 64);
        if (threadIdx.x == 0) out[0] = v / (float)BATCH;
    }
}

// ---------------------------------------------------------------------------
extern "C" void kernel_launch(void* const* d_in, const int* in_sizes, int n_in,
                              void* d_out, int out_size, void* d_ws, size_t ws_size,
                              hipStream_t stream)
{
    const float* emb    = (const float*)d_in[0];
    const int*   labels = (const int*)d_in[1];
    float*       out    = (float*)d_out;

    char* ws = (char*)d_ws;
    __hip_bfloat16* EbfA = (__hip_bfloat16*)ws;                       // 2.56 MiB
    __hip_bfloat16* EbfB = (__hip_bfloat16*)(ws + 3  * 1024 * 1024);  // 2.56 MiB
    float*    sq   = (float*)   (ws + 6 * 1024 * 1024);               // 32 KiB
    unsigned* hp2  = (unsigned*)(ws + 6 * 1024 * 1024 + 32 * 1024);   // 32 KiB
    unsigned* hn2  = (unsigned*)(ws + 6 * 1024 * 1024 + 64 * 1024);   // 32 KiB

    bhtl_prep<<<BATCH / 4, 256, 0, stream>>>(emb, labels, EbfA, EbfB, sq, hp2, hn2);
    bhtl_main<<<1024, 128, 0, stream>>>(EbfA, EbfB, sq, hp2, hn2);
    bhtl_final<<<1, 1024, 0, stream>>>(hp2, hn2, out);
}